// Round 4
// baseline (201.022 us; speedup 1.0000x reference)
//
#include <hip/hip_runtime.h>

#define IMG_H 480
#define IMG_W 480
#define ATT_H 30
#define ATT_W 30
#define ATT_N (ATT_H * ATT_W)
#define PAD 48
#define NCH 3
#define NB 32
#define STRIPS 16           // 480 rows / 30 rows per strip
#define ROWS_PER_STRIP 30

// Kernel 1: per-strip mask bbox. Each block computes theta (0.5*max) itself
// (deterministic, identical across blocks) and writes its strip's raw bbox to
// a private slot — no global atomics, no init dependency on ws contents.
__global__ void __launch_bounds__(256) mask_kernel(const float* __restrict__ atten,
                                                   int* __restrict__ strip_box) {
    const int strip = blockIdx.x;
    const int b = blockIdx.y;
    const int tid = threadIdx.x;
    __shared__ float s_att[ATT_N];
    __shared__ float s_red[4];
    __shared__ int s_box[4];   // minr, maxr, minc, maxc

    const float* a = atten + (size_t)b * ATT_N;
    for (int i = tid; i < ATT_N; i += 256) s_att[i] = a[i];
    if (tid == 0) { s_box[0] = IMG_H; s_box[1] = -1; s_box[2] = IMG_W; s_box[3] = -1; }
    __syncthreads();

    // block max over the 900 attention values (order-independent => exact)
    float m = -1e30f;
    for (int i = tid; i < ATT_N; i += 256) m = fmaxf(m, s_att[i]);
    #pragma unroll
    for (int off = 32; off > 0; off >>= 1) m = fmaxf(m, __shfl_down(m, off, 64));
    if ((tid & 63) == 0) s_red[tid >> 6] = m;
    __syncthreads();
    const float theta = 0.5f * fmaxf(fmaxf(s_red[0], s_red[1]), fmaxf(s_red[2], s_red[3]));

    const int y_base = strip * ROWS_PER_STRIP;
    int minr = IMG_H, maxr = -1, minc = IMG_W, maxc = -1;
    for (int p = tid; p < ROWS_PER_STRIP * IMG_W; p += 256) {
        const int yy = p / IMG_W;
        const int y = y_base + yy;
        const int x = p - yy * IMG_W;
        // source coords: (i+0.5)*(30/480) - 0.5, clipped — scale is exactly 1/16
        float sy = (y + 0.5f) * 0.0625f - 0.5f;
        sy = fminf(fmaxf(sy, 0.0f), (float)(ATT_H - 1));
        const float fy0 = floorf(sy);
        const int r0 = (int)fy0;
        const int r1 = min(r0 + 1, ATT_H - 1);
        const float wr = sy - fy0;

        float sx = (x + 0.5f) * 0.0625f - 0.5f;
        sx = fminf(fmaxf(sx, 0.0f), (float)(ATT_W - 1));
        const float fx0 = floorf(sx);
        const int c0 = (int)fx0;
        const int c1 = min(c0 + 1, ATT_W - 1);
        const float wc = sx - fx0;

        // same op order as reference: row blend first, then column blend
        const float rb0 = s_att[r0 * ATT_W + c0] * (1.0f - wr) + s_att[r1 * ATT_W + c0] * wr;
        const float rb1 = s_att[r0 * ATT_W + c1] * (1.0f - wr) + s_att[r1 * ATT_W + c1] * wr;
        const float v = rb0 * (1.0f - wc) + rb1 * wc;
        if (v >= theta) {
            minr = min(minr, y); maxr = max(maxr, y);
            minc = min(minc, x); maxc = max(maxc, x);
        }
    }
    atomicMin(&s_box[0], minr); atomicMax(&s_box[1], maxr);
    atomicMin(&s_box[2], minc); atomicMax(&s_box[3], maxc);
    __syncthreads();
    if (tid == 0) {
        int* dst = strip_box + ((size_t)b * STRIPS + strip) * 4;
        dst[0] = s_box[0]; dst[1] = s_box[1]; dst[2] = s_box[2]; dst[3] = s_box[3];
    }
}

// Kernel 2: one block per (b, c, y) output row, 256 threads.
// Strided pixel ownership (x = tid, tid+256) keeps LDS gather reads at
// lane-stride ~1 element => conflict-free (2-way aliasing is free on gfx950).
// Staging of both source rows happens in a single phase (half-block each).
__global__ void __launch_bounds__(256) blend_kernel(const float* __restrict__ images,
                                                    const int* __restrict__ strip_box,
                                                    float* __restrict__ out) {
    const int y = blockIdx.x;
    const int c = blockIdx.y;
    const int b = blockIdx.z;
    const int tid = threadIdx.x;
    __shared__ float s_r0[IMG_W];
    __shared__ float s_r1[IMG_W];

    // reduce strip bboxes (uniform, L2-hit)
    int minr = IMG_H, maxr = -1, minc = IMG_W, maxc = -1;
    const int* sb = strip_box + (size_t)b * STRIPS * 4;
    #pragma unroll
    for (int s = 0; s < STRIPS; ++s) {
        minr = min(minr, sb[s * 4 + 0]); maxr = max(maxr, sb[s * 4 + 1]);
        minc = min(minc, sb[s * 4 + 2]); maxc = max(maxc, sb[s * 4 + 3]);
    }
    const int h0 = max(minr - PAD, 0);
    const int h1 = min(maxr + PAD, IMG_H);
    const int w0 = max(minc - PAD, 0);
    const int w1 = min(maxc + PAD, IMG_W);
    const float cropH = (float)(h1 - h0);
    const float cropW = (float)(w1 - w0);

    // row coords for this output row (reference op order)
    float sy = (y + 0.5f) * (cropH / (float)IMG_H) - 0.5f;
    sy = fminf(fmaxf(sy, 0.0f), cropH - 1.0f);
    const float fy0 = floorf(sy);
    const float fy1 = fminf(fy0 + 1.0f, cropH - 1.0f);
    const float wr = sy - fy0;
    const int r0 = h0 + (int)fy0;
    const int r1 = h0 + (int)fy1;

    const float* img = images + ((size_t)b * NCH + c) * (IMG_H * IMG_W);

    // stage both source rows in ONE phase: threads [0,120) do r0, [128,248) do r1
    if (tid < IMG_W / 4) {
        ((float4*)s_r0)[tid] = ((const float4*)(img + (size_t)r0 * IMG_W))[tid];
    } else if (tid >= 128 && tid < 128 + IMG_W / 4) {
        ((float4*)s_r1)[tid - 128] = ((const float4*)(img + (size_t)r1 * IMG_W))[tid - 128];
    }
    __syncthreads();

    const float scaleW = cropW / (float)IMG_W;
    const float* row_in = img + (size_t)y * IMG_W;
    float* row_out = out + ((size_t)b * NCH + c) * (IMG_H * IMG_W) + (size_t)y * IMG_W;

    #pragma unroll
    for (int j = 0; j < 2; ++j) {
        const int x = tid + j * 256;
        if (x < IMG_W) {
            float sx = (x + 0.5f) * scaleW - 0.5f;
            sx = fminf(fmaxf(sx, 0.0f), cropW - 1.0f);
            const float fx0 = floorf(sx);
            const float fx1 = fminf(fx0 + 1.0f, cropW - 1.0f);
            const float wc = sx - fx0;
            const int c0 = w0 + (int)fx0;
            const int c1 = w0 + (int)fx1;

            const float v00 = s_r0[c0];
            const float v10 = s_r1[c0];
            const float v01 = s_r0[c1];
            const float v11 = s_r1[c1];
            const float rb0 = v00 * (1.0f - wr) + v10 * wr;
            const float rb1 = v01 * (1.0f - wr) + v11 * wr;
            const float patch = rb0 * (1.0f - wc) + rb1 * wc;
            row_out[x] = row_in[x] * 0.6f + patch * 0.4f;
        }
    }
}

extern "C" void kernel_launch(void* const* d_in, const int* in_sizes, int n_in,
                              void* d_out, int out_size, void* d_ws, size_t ws_size,
                              hipStream_t stream) {
    const float* images = (const float*)d_in[0];
    const float* atten  = (const float*)d_in[1];
    float* out = (float*)d_out;
    int* strip_box = (int*)d_ws;   // 32 * 16 * 4 ints

    dim3 mgrid(STRIPS, NB);
    mask_kernel<<<mgrid, 256, 0, stream>>>(atten, strip_box);

    dim3 bgrid(IMG_H, NCH, NB);
    blend_kernel<<<bgrid, 256, 0, stream>>>(images, strip_box, out);
}

// Round 5
// 191.565 us; speedup vs baseline: 1.0494x; 1.0494x over previous
//
#include <hip/hip_runtime.h>

#define IMG_H 480
#define IMG_W 480
#define ATT_H 30
#define ATT_W 30
#define ATT_N (ATT_H * ATT_W)
#define PAD 48
#define NCH 3
#define NB 32
#define STRIPS 16           // 480 rows / 30 rows per strip
#define ROWS_PER_STRIP 30

// Kernel 1: per-strip mask bbox. Each block computes theta (0.5*max) itself
// (deterministic, identical across blocks) and writes its strip's raw bbox to
// a private slot — no global atomics, no init dependency on ws contents.
__global__ void __launch_bounds__(256) mask_kernel(const float* __restrict__ atten,
                                                   int* __restrict__ strip_box) {
    const int strip = blockIdx.x;
    const int b = blockIdx.y;
    const int tid = threadIdx.x;
    __shared__ float s_att[ATT_N];
    __shared__ float s_red[4];
    __shared__ int s_box[4];   // minr, maxr, minc, maxc

    const float* a = atten + (size_t)b * ATT_N;
    for (int i = tid; i < ATT_N; i += 256) s_att[i] = a[i];
    if (tid == 0) { s_box[0] = IMG_H; s_box[1] = -1; s_box[2] = IMG_W; s_box[3] = -1; }
    __syncthreads();

    // block max over the 900 attention values (order-independent => exact)
    float m = -1e30f;
    for (int i = tid; i < ATT_N; i += 256) m = fmaxf(m, s_att[i]);
    #pragma unroll
    for (int off = 32; off > 0; off >>= 1) m = fmaxf(m, __shfl_down(m, off, 64));
    if ((tid & 63) == 0) s_red[tid >> 6] = m;
    __syncthreads();
    const float theta = 0.5f * fmaxf(fmaxf(s_red[0], s_red[1]), fmaxf(s_red[2], s_red[3]));

    const int y_base = strip * ROWS_PER_STRIP;
    int minr = IMG_H, maxr = -1, minc = IMG_W, maxc = -1;
    for (int p = tid; p < ROWS_PER_STRIP * IMG_W; p += 256) {
        const int yy = p / IMG_W;
        const int y = y_base + yy;
        const int x = p - yy * IMG_W;
        // source coords: (i+0.5)*(30/480) - 0.5, clipped — scale is exactly 1/16
        float sy = (y + 0.5f) * 0.0625f - 0.5f;
        sy = fminf(fmaxf(sy, 0.0f), (float)(ATT_H - 1));
        const float fy0 = floorf(sy);
        const int r0 = (int)fy0;
        const int r1 = min(r0 + 1, ATT_H - 1);
        const float wr = sy - fy0;

        float sx = (x + 0.5f) * 0.0625f - 0.5f;
        sx = fminf(fmaxf(sx, 0.0f), (float)(ATT_W - 1));
        const float fx0 = floorf(sx);
        const int c0 = (int)fx0;
        const int c1 = min(c0 + 1, ATT_W - 1);
        const float wc = sx - fx0;

        // same op order as reference: row blend first, then column blend
        const float rb0 = s_att[r0 * ATT_W + c0] * (1.0f - wr) + s_att[r1 * ATT_W + c0] * wr;
        const float rb1 = s_att[r0 * ATT_W + c1] * (1.0f - wr) + s_att[r1 * ATT_W + c1] * wr;
        const float v = rb0 * (1.0f - wc) + rb1 * wc;
        if (v >= theta) {
            minr = min(minr, y); maxr = max(maxr, y);
            minc = min(minc, x); maxc = max(maxc, x);
        }
    }
    atomicMin(&s_box[0], minr); atomicMax(&s_box[1], maxr);
    atomicMin(&s_box[2], minc); atomicMax(&s_box[3], maxc);
    __syncthreads();
    if (tid == 0) {
        int* dst = strip_box + ((size_t)b * STRIPS + strip) * 4;
        dst[0] = s_box[0]; dst[1] = s_box[1]; dst[2] = s_box[2]; dst[3] = s_box[3];
    }
}

// Kernel 2: one block per (b, c, y) output row, 256 threads.
// Phase 1: float4-stage source rows r0/r1 into LDS; storing threads also
//          pre-load their base-row float4 into registers.
// Phase 2: compute patch at x = tid (+256) — lane-stride-1 LDS gathers are
//          broadcast/2-way => conflict-free; write scalar to s_out[x].
// Phase 3: threads 0..119 read s_out as float4 (16B/lane, conflict-free),
//          blend with registered base, float4 store. All global I/O is x4.
__global__ void __launch_bounds__(256) blend_kernel(const float* __restrict__ images,
                                                    const int* __restrict__ strip_box,
                                                    float* __restrict__ out) {
    const int y = blockIdx.x;
    const int c = blockIdx.y;
    const int b = blockIdx.z;
    const int tid = threadIdx.x;
    __shared__ float s_r0[IMG_W];
    __shared__ float s_r1[IMG_W];
    __shared__ float s_out[IMG_W];

    // reduce strip bboxes (block-uniform => scalar loads, L2-hit)
    int minr = IMG_H, maxr = -1, minc = IMG_W, maxc = -1;
    const int* sb = strip_box + (size_t)b * STRIPS * 4;
    #pragma unroll
    for (int s = 0; s < STRIPS; ++s) {
        minr = min(minr, sb[s * 4 + 0]); maxr = max(maxr, sb[s * 4 + 1]);
        minc = min(minc, sb[s * 4 + 2]); maxc = max(maxc, sb[s * 4 + 3]);
    }
    const int h0 = max(minr - PAD, 0);
    const int h1 = min(maxr + PAD, IMG_H);
    const int w0 = max(minc - PAD, 0);
    const int w1 = min(maxc + PAD, IMG_W);
    const float cropH = (float)(h1 - h0);
    const float cropW = (float)(w1 - w0);

    // row coords for this output row (reference op order)
    float sy = (y + 0.5f) * (cropH / (float)IMG_H) - 0.5f;
    sy = fminf(fmaxf(sy, 0.0f), cropH - 1.0f);
    const float fy0 = floorf(sy);
    const float fy1 = fminf(fy0 + 1.0f, cropH - 1.0f);
    const float wr = sy - fy0;
    const int r0 = h0 + (int)fy0;
    const int r1 = h0 + (int)fy1;

    const float* img = images + ((size_t)b * NCH + c) * (IMG_H * IMG_W);

    // Phase 1: stage r0 (threads 0..119) and r1 (threads 128..247); the
    // storing threads (0..119) also pre-load their base-row float4.
    float4 base = make_float4(0.f, 0.f, 0.f, 0.f);
    if (tid < IMG_W / 4) {
        ((float4*)s_r0)[tid] = ((const float4*)(img + (size_t)r0 * IMG_W))[tid];
        base = ((const float4*)(img + (size_t)y * IMG_W))[tid];
    } else if (tid >= 128 && tid < 128 + IMG_W / 4) {
        ((float4*)s_r1)[tid - 128] = ((const float4*)(img + (size_t)r1 * IMG_W))[tid - 128];
    }
    __syncthreads();

    // Phase 2: conflict-free gathers, scalar patch into s_out
    const float scaleW = cropW / (float)IMG_W;
    #pragma unroll
    for (int j = 0; j < 2; ++j) {
        const int x = tid + j * 256;
        if (x < IMG_W) {
            float sx = (x + 0.5f) * scaleW - 0.5f;
            sx = fminf(fmaxf(sx, 0.0f), cropW - 1.0f);
            const float fx0 = floorf(sx);
            const float fx1 = fminf(fx0 + 1.0f, cropW - 1.0f);
            const float wc = sx - fx0;
            const int c0 = w0 + (int)fx0;
            const int c1 = w0 + (int)fx1;

            const float v00 = s_r0[c0];
            const float v10 = s_r1[c0];
            const float v01 = s_r0[c1];
            const float v11 = s_r1[c1];
            const float rb0 = v00 * (1.0f - wr) + v10 * wr;
            const float rb1 = v01 * (1.0f - wr) + v11 * wr;
            s_out[x] = rb0 * (1.0f - wc) + rb1 * wc;
        }
    }
    __syncthreads();

    // Phase 3: vectorized blend + store
    if (tid < IMG_W / 4) {
        const float4 o = ((const float4*)s_out)[tid];
        float4 res;
        res.x = base.x * 0.6f + o.x * 0.4f;
        res.y = base.y * 0.6f + o.y * 0.4f;
        res.z = base.z * 0.6f + o.z * 0.4f;
        res.w = base.w * 0.6f + o.w * 0.4f;
        ((float4*)(out + ((size_t)b * NCH + c) * (IMG_H * IMG_W) + (size_t)y * IMG_W))[tid] = res;
    }
}

extern "C" void kernel_launch(void* const* d_in, const int* in_sizes, int n_in,
                              void* d_out, int out_size, void* d_ws, size_t ws_size,
                              hipStream_t stream) {
    const float* images = (const float*)d_in[0];
    const float* atten  = (const float*)d_in[1];
    float* out = (float*)d_out;
    int* strip_box = (int*)d_ws;   // 32 * 16 * 4 ints

    dim3 mgrid(STRIPS, NB);
    mask_kernel<<<mgrid, 256, 0, stream>>>(atten, strip_box);

    dim3 bgrid(IMG_H, NCH, NB);
    blend_kernel<<<bgrid, 256, 0, stream>>>(images, strip_box, out);
}

// Round 6
// 189.129 us; speedup vs baseline: 1.0629x; 1.0129x over previous
//
#include <hip/hip_runtime.h>

#define IMG_H 480
#define IMG_W 480
#define ATT_H 30
#define ATT_W 30
#define ATT_N (ATT_H * ATT_W)
#define PAD 48
#define NCH 3
#define NB 32
#define STRIPS 16           // 480 rows / 30 rows per strip
#define ROWS_PER_STRIP 30
#define W4 (IMG_W / 4)      // 120 float4 per row

// Kernel 1: per-strip mask bbox. Each block computes theta (0.5*max) itself
// (deterministic, identical across blocks) and writes its strip's raw bbox to
// a private slot — no global atomics, no init dependency on ws contents.
__global__ void __launch_bounds__(256) mask_kernel(const float* __restrict__ atten,
                                                   int* __restrict__ strip_box) {
    const int strip = blockIdx.x;
    const int b = blockIdx.y;
    const int tid = threadIdx.x;
    __shared__ float s_att[ATT_N];
    __shared__ float s_red[4];
    __shared__ int s_box[4];   // minr, maxr, minc, maxc

    const float* a = atten + (size_t)b * ATT_N;
    for (int i = tid; i < ATT_N; i += 256) s_att[i] = a[i];
    if (tid == 0) { s_box[0] = IMG_H; s_box[1] = -1; s_box[2] = IMG_W; s_box[3] = -1; }
    __syncthreads();

    // block max over the 900 attention values (order-independent => exact)
    float m = -1e30f;
    for (int i = tid; i < ATT_N; i += 256) m = fmaxf(m, s_att[i]);
    #pragma unroll
    for (int off = 32; off > 0; off >>= 1) m = fmaxf(m, __shfl_down(m, off, 64));
    if ((tid & 63) == 0) s_red[tid >> 6] = m;
    __syncthreads();
    const float theta = 0.5f * fmaxf(fmaxf(s_red[0], s_red[1]), fmaxf(s_red[2], s_red[3]));

    const int y_base = strip * ROWS_PER_STRIP;
    int minr = IMG_H, maxr = -1, minc = IMG_W, maxc = -1;
    for (int p = tid; p < ROWS_PER_STRIP * IMG_W; p += 256) {
        const int yy = p / IMG_W;
        const int y = y_base + yy;
        const int x = p - yy * IMG_W;
        // source coords: (i+0.5)*(30/480) - 0.5, clipped — scale is exactly 1/16
        float sy = (y + 0.5f) * 0.0625f - 0.5f;
        sy = fminf(fmaxf(sy, 0.0f), (float)(ATT_H - 1));
        const float fy0 = floorf(sy);
        const int r0 = (int)fy0;
        const int r1 = min(r0 + 1, ATT_H - 1);
        const float wr = sy - fy0;

        float sx = (x + 0.5f) * 0.0625f - 0.5f;
        sx = fminf(fmaxf(sx, 0.0f), (float)(ATT_W - 1));
        const float fx0 = floorf(sx);
        const int c0 = (int)fx0;
        const int c1 = min(c0 + 1, ATT_W - 1);
        const float wc = sx - fx0;

        // same op order as reference: row blend first, then column blend
        const float rb0 = s_att[r0 * ATT_W + c0] * (1.0f - wr) + s_att[r1 * ATT_W + c0] * wr;
        const float rb1 = s_att[r0 * ATT_W + c1] * (1.0f - wr) + s_att[r1 * ATT_W + c1] * wr;
        const float v = rb0 * (1.0f - wc) + rb1 * wc;
        if (v >= theta) {
            minr = min(minr, y); maxr = max(maxr, y);
            minc = min(minc, x); maxc = max(maxc, x);
        }
    }
    atomicMin(&s_box[0], minr); atomicMax(&s_box[1], maxr);
    atomicMin(&s_box[2], minc); atomicMax(&s_box[3], maxc);
    __syncthreads();
    if (tid == 0) {
        int* dst = strip_box + ((size_t)b * STRIPS + strip) * 4;
        dst[0] = s_box[0]; dst[1] = s_box[1]; dst[2] = s_box[2]; dst[3] = s_box[3];
    }
}

// Kernel 2: one block per (b, y) output row — ALL 3 channels per block.
// Column coords computed once per x and reused across channels (3x VALU cut);
// bbox reduce + row coords amortized 3x. All global I/O is float4; LDS access
// patterns are stride-1 / 16B-per-lane => conflict-free.
__global__ void __launch_bounds__(256) blend_kernel(const float* __restrict__ images,
                                                    const int* __restrict__ strip_box,
                                                    float* __restrict__ out) {
    const int y = blockIdx.x;
    const int b = blockIdx.y;
    const int tid = threadIdx.x;
    __shared__ float s_rows[NCH][2][IMG_W];   // [ch][r0|r1][x]
    __shared__ float s_out[NCH][IMG_W];

    // reduce strip bboxes (block-uniform => scalar loads, L2-hit)
    int minr = IMG_H, maxr = -1, minc = IMG_W, maxc = -1;
    const int* sb = strip_box + (size_t)b * STRIPS * 4;
    #pragma unroll
    for (int s = 0; s < STRIPS; ++s) {
        minr = min(minr, sb[s * 4 + 0]); maxr = max(maxr, sb[s * 4 + 1]);
        minc = min(minc, sb[s * 4 + 2]); maxc = max(maxc, sb[s * 4 + 3]);
    }
    const int h0 = max(minr - PAD, 0);
    const int h1 = min(maxr + PAD, IMG_H);
    const int w0 = max(minc - PAD, 0);
    const int w1 = min(maxc + PAD, IMG_W);
    const float cropH = (float)(h1 - h0);
    const float cropW = (float)(w1 - w0);

    // row coords for this output row (reference op order)
    float sy = (y + 0.5f) * (cropH / (float)IMG_H) - 0.5f;
    sy = fminf(fmaxf(sy, 0.0f), cropH - 1.0f);
    const float fy0 = floorf(sy);
    const float fy1 = fminf(fy0 + 1.0f, cropH - 1.0f);
    const float wr = sy - fy0;
    const int r0 = h0 + (int)fy0;
    const int r1 = h0 + (int)fy1;

    const float* img = images + (size_t)b * NCH * IMG_H * IMG_W;

    // Phase 1: stage 6 source rows (3 ch x {r0, r1}) as float4; the storing
    // threads (0..119) also pre-load their base-row float4 per channel.
    for (int i = tid; i < NCH * 2 * W4; i += 256) {
        const int ch = i / (2 * W4);
        const int rem = i - ch * (2 * W4);
        const int rr = rem / W4;
        const int seg = rem - rr * W4;
        const int srcrow = (rr == 0) ? r0 : r1;
        ((float4*)s_rows[ch][rr])[seg] =
            ((const float4*)(img + ((size_t)ch * IMG_H + srcrow) * IMG_W))[seg];
    }
    float4 base[NCH];
    if (tid < W4) {
        #pragma unroll
        for (int ch = 0; ch < NCH; ++ch)
            base[ch] = ((const float4*)(img + ((size_t)ch * IMG_H + y) * IMG_W))[tid];
    }
    __syncthreads();

    // Phase 2: column coords once per x, gather all 3 channels from LDS
    const float scaleW = cropW / (float)IMG_W;
    const float wr1 = 1.0f - wr;
    #pragma unroll
    for (int j = 0; j < 2; ++j) {
        const int x = tid + j * 256;
        if (x < IMG_W) {
            float sx = (x + 0.5f) * scaleW - 0.5f;
            sx = fminf(fmaxf(sx, 0.0f), cropW - 1.0f);
            const float fx0 = floorf(sx);
            const float fx1 = fminf(fx0 + 1.0f, cropW - 1.0f);
            const float wc = sx - fx0;
            const float wc1 = 1.0f - wc;
            const int c0 = w0 + (int)fx0;
            const int c1 = w0 + (int)fx1;

            #pragma unroll
            for (int ch = 0; ch < NCH; ++ch) {
                const float v00 = s_rows[ch][0][c0];
                const float v10 = s_rows[ch][1][c0];
                const float v01 = s_rows[ch][0][c1];
                const float v11 = s_rows[ch][1][c1];
                const float rb0 = v00 * wr1 + v10 * wr;
                const float rb1 = v01 * wr1 + v11 * wr;
                s_out[ch][x] = rb0 * wc1 + rb1 * wc;
            }
        }
    }
    __syncthreads();

    // Phase 3: vectorized blend + store, 3 channels
    if (tid < W4) {
        #pragma unroll
        for (int ch = 0; ch < NCH; ++ch) {
            const float4 o = ((const float4*)s_out[ch])[tid];
            float4 res;
            res.x = base[ch].x * 0.6f + o.x * 0.4f;
            res.y = base[ch].y * 0.6f + o.y * 0.4f;
            res.z = base[ch].z * 0.6f + o.z * 0.4f;
            res.w = base[ch].w * 0.6f + o.w * 0.4f;
            ((float4*)(out + ((size_t)b * NCH + ch) * (IMG_H * IMG_W) + (size_t)y * IMG_W))[tid] = res;
        }
    }
}

extern "C" void kernel_launch(void* const* d_in, const int* in_sizes, int n_in,
                              void* d_out, int out_size, void* d_ws, size_t ws_size,
                              hipStream_t stream) {
    const float* images = (const float*)d_in[0];
    const float* atten  = (const float*)d_in[1];
    float* out = (float*)d_out;
    int* strip_box = (int*)d_ws;   // 32 * 16 * 4 ints

    dim3 mgrid(STRIPS, NB);
    mask_kernel<<<mgrid, 256, 0, stream>>>(atten, strip_box);

    dim3 bgrid(IMG_H, NB);
    blend_kernel<<<bgrid, 256, 0, stream>>>(images, strip_box, out);
}